// Round 14
// baseline (633.977 us; speedup 1.0000x reference)
//
#include <hip/hip_runtime.h>

// GRU: B=4096, T=512, I=32, H=64. One WG per 16-batch tile, 4 waves.
// R10: TWO-RECURRENCE INTERLEAVE. (Round 13: verbatim resubmit — Rounds
// 11+12 proposals hit GPUAcquisitionTimeout, kernel never ran.)
// Evidence: R6 (8 lockstep waves) and R9 (2 independent WGs/CU) both
// REGRESSED -> extra waves always add >=2x duplicated issue; occupancy
// axis closed. R5b/R7 counters: step = 1110 cyc but only ~430 cyc VALU
// issue + ~145 cyc MFMA -> ~60% is the serial chain (ds_read -> MFMA
// deps -> epilogue chain -> write -> barrier) that one wave can't
// overlap WITH ITSELF.
// Fix: split the 16-batch tile into two 8-batch tiles A,B carried by
// the SAME 4 waves, ONE barrier per pair-step. A and B are independent
// dataflows: B's issue fills A's chain stalls and vice versa. No extra
// waves, no extra barriers per tile-step (0.5 barrier/tile-step).
// Price: B-operand cols 8-15 are duplicates (2x MFMA, affordable at
// 13% MfmaUtil; junk cols compute bit-identical duplicate batches ->
// bounded by induction), and junk-lane epilogues (40 trans/pair).
// Weights/biases shared between tiles (same hidden slice per wave).
// Carries R5b/R7: untracked asm loads (4-slot chunks x2 tiles),
// data-dep vmcnt drains, raw lgkmcnt+s_barrier, merged-rcp epilogue,
// pre-barrier x-proj. __launch_bounds__(256,1): 1 wave/SIMD is
// structural; ~240 VGPR free.

#define TSTEPS 512
#define IDIM 32
#define HDIM 64

typedef __bf16 bf16x8 __attribute__((ext_vector_type(8)));
typedef __bf16 bf16x4 __attribute__((ext_vector_type(4)));
typedef float f32x4 __attribute__((ext_vector_type(4)));

#define NLOG2E -1.4426950408889634f
#define TWOLOG2E 2.8853900817779268f

#define LOADPAIR(dst0, dst1, ptr, off)                                     \
    asm volatile("global_load_dwordx4 %0, %2, off offset:%c3\n\t"          \
                 "global_load_dwordx4 %1, %2, off offset:%c4"              \
        : "=&v"(dst0), "=&v"(dst1)                                         \
        : "v"(ptr), "i"(off), "i"((off) + 16));

// One 4-timestep chunk (512 B/lane) as 8 untracked global_load_dwordx4.
#define ISSUE_CHUNK(qq, rowPtr, baseT) do {                                \
    const float* _p = rowPtr + (size_t)(baseT) * IDIM;                     \
    LOADPAIR(qq[0][0], qq[0][1], _p, 0)                                    \
    LOADPAIR(qq[1][0], qq[1][1], _p, 128)                                  \
    LOADPAIR(qq[2][0], qq[2][1], _p, 256)                                  \
    LOADPAIR(qq[3][0], qq[3][1], _p, 384)                                  \
} while (0)

#define WAITDEP(qq)                                                        \
    asm volatile("s_waitcnt vmcnt(0)"                                      \
        : "+v"(qq[0][0]), "+v"(qq[0][1]), "+v"(qq[1][0]), "+v"(qq[1][1]), \
          "+v"(qq[2][0]), "+v"(qq[2][1]), "+v"(qq[3][0]), "+v"(qq[3][1]))

#define WG_BARRIER() do {                                                  \
    asm volatile("s_waitcnt lgkmcnt(0)" ::: "memory");                     \
    __builtin_amdgcn_s_barrier();                                          \
} while (0)

#define MFMA16(a, b, c) __builtin_amdgcn_mfma_f32_16x16x32_bf16(a, b, c, 0, 0, 0)

__global__ __launch_bounds__(256, 1) void gru_fused_kernel(
    const float* __restrict__ seq, const float* __restrict__ W_ih,
    const float* __restrict__ W_hh, const float* __restrict__ b_ih,
    const float* __restrict__ b_hh, float* __restrict__ out)
{
    __shared__ __bf16 hA[2][16][72];   // tile A h^T, double-buffered
    __shared__ __bf16 hBt[2][16][72];  // tile B h^T

    const int tid  = threadIdx.x;
    const int w    = tid >> 6;
    const int lane = tid & 63;
    const int l    = lane & 15;        // B-fragment col (batch); 8-15 duplicate
    const int q    = lane >> 4;
    const int b0   = blockIdx.x * 16;  // tile A = b0..b0+7, tile B = b0+8..b0+15

    for (int i = tid; i < 2 * 16 * 72; i += 256) (&hA[0][0][0])[i]  = (__bf16)0.0f;
    for (int i = tid; i < 2 * 16 * 72; i += 256) (&hBt[0][0][0])[i] = (__bf16)0.0f;

    // ---- shared A-fragments (same hidden slice for both tiles) ----
    bf16x8 aH[3][2], aI[3];
    #pragma unroll
    for (int g = 0; g < 3; ++g) {
        const float scl = (g < 2) ? NLOG2E : TWOLOG2E;
        const int row = g * 64 + w * 16 + l;
        #pragma unroll
        for (int kc = 0; kc < 2; ++kc) {
            const float* p = W_hh + row * HDIM + kc * 32 + q * 8;
            #pragma unroll
            for (int j = 0; j < 8; ++j) aH[g][kc][j] = (__bf16)(scl * p[j]);
        }
        const float* pi = W_ih + row * IDIM + q * 8;
        #pragma unroll
        for (int j = 0; j < 8; ++j) aI[g][j] = (__bf16)(scl * pi[j]);
    }

    f32x4 biasR4, biasZ4, biasXN4, biasHN4;
    #pragma unroll
    for (int r = 0; r < 4; ++r) {
        const int g = w * 16 + 4 * q + r;
        biasR4[r]  = NLOG2E * (b_ih[g]      + b_hh[g]);
        biasZ4[r]  = NLOG2E * (b_ih[64 + g] + b_hh[64 + g]);
        biasXN4[r] = TWOLOG2E * b_ih[128 + g];
        biasHN4[r] = TWOLOG2E * b_hh[128 + g];
    }

    float hA_r[4] = {0.f, 0.f, 0.f, 0.f};
    float hB_r[4] = {0.f, 0.f, 0.f, 0.f};

    // lanes l>=8 load duplicate batch (l&7): junk cols evolve as exact
    // duplicates of cols l-8 -> bounded by induction.
    const float* seqRowA = seq + ((size_t)(b0 + (l & 7)) * TSTEPS) * IDIM + q * 8;
    const float* seqRowB = seq + ((size_t)(b0 + 8 + (l & 7)) * TSTEPS) * IDIM + q * 8;

    f32x4 qAA[4][2], qBA[4][2];  // tile A: chunks [tc,tc+4), [tc+4,tc+8)
    f32x4 qAB[4][2], qBB[4][2];  // tile B
    ISSUE_CHUNK(qAA, seqRowA, 0);
    ISSUE_CHUNK(qAB, seqRowB, 0);
    ISSUE_CHUNK(qBA, seqRowA, 4);
    ISSUE_CHUNK(qBB, seqRowB, 4);
    WAITDEP(qAA); WAITDEP(qAB); WAITDEP(qBA); WAITDEP(qBB);

    WG_BARRIER();   // zero-init visible

    // ---- t=0 x-proj for both tiles (bias-init C) ----
    bf16x8 xbA, xbB;
    #pragma unroll
    for (int j = 0; j < 4; ++j) {
        xbA[j] = (__bf16)qAA[0][0][j];  xbA[4 + j] = (__bf16)qAA[0][1][j];
        xbB[j] = (__bf16)qAB[0][0][j];  xbB[4 + j] = (__bf16)qAB[0][1][j];
    }
    f32x4 accAR  = MFMA16(aI[0], xbA, biasR4);
    f32x4 accAZ  = MFMA16(aI[1], xbA, biasZ4);
    f32x4 accAXN = MFMA16(aI[2], xbA, biasXN4);
    f32x4 accBR  = MFMA16(aI[0], xbB, biasR4);
    f32x4 accBZ  = MFMA16(aI[1], xbB, biasZ4);
    f32x4 accBXN = MFMA16(aI[2], xbB, biasXN4);

    for (int tc = 0; tc < TSTEPS; tc += 8) {
        #pragma unroll
        for (int s = 0; s < 8; ++s) {
            const int buf = s & 1;

            // issue all 4 h^T reads first (latency overlap across tiles)
            bf16x8 a0 = *(const bf16x8*)&hA[buf][l][q * 8];
            bf16x8 a1 = *(const bf16x8*)&hA[buf][l][32 + q * 8];
            bf16x8 c0 = *(const bf16x8*)&hBt[buf][l][q * 8];
            bf16x8 c1 = *(const bf16x8*)&hBt[buf][l][32 + q * 8];

            // ---- tile A: H-MFMAs ----
            accAR = MFMA16(aH[0][0], a0, accAR);
            accAZ = MFMA16(aH[1][0], a0, accAZ);
            f32x4 accAHN = MFMA16(aH[2][0], a0, biasHN4);
            accAR = MFMA16(aH[0][1], a1, accAR);
            accAZ = MFMA16(aH[1][1], a1, accAZ);
            accAHN = MFMA16(aH[2][1], a1, accAHN);

            // ---- tile B: H-MFMAs (independent chain) ----
            accBR = MFMA16(aH[0][0], c0, accBR);
            accBZ = MFMA16(aH[1][0], c0, accBZ);
            f32x4 accBHN = MFMA16(aH[2][0], c0, biasHN4);
            accBR = MFMA16(aH[0][1], c1, accBR);
            accBZ = MFMA16(aH[1][1], c1, accBZ);
            accBHN = MFMA16(aH[2][1], c1, accBHN);

            // ---- epilogues (merged-rcp, R7 formula); A then B — the
            // compiler interleaves the independent chains ----
            bf16x4 hOutA, hOutB;
            #pragma unroll
            for (int r = 0; r < 4; ++r) {
                const float R  = __builtin_amdgcn_exp2f(accAR[r]);
                const float rg = __builtin_amdgcn_rcpf(R + 1.0f);
                const float v2 = __builtin_fmaf(rg, accAHN[r], accAXN[r]);
                const float U  = __builtin_amdgcn_exp2f(v2);
                const float Z  = __builtin_amdgcn_exp2f(accAZ[r]);
                const float num = __builtin_fmaf(U, Z + hA_r[r], hA_r[r] - Z);
                const float den = (U + 1.0f) * (Z + 1.0f);
                hA_r[r] = num * __builtin_amdgcn_rcpf(den);
                hOutA[r] = (__bf16)hA_r[r];
            }
            #pragma unroll
            for (int r = 0; r < 4; ++r) {
                const float R  = __builtin_amdgcn_exp2f(accBR[r]);
                const float rg = __builtin_amdgcn_rcpf(R + 1.0f);
                const float v2 = __builtin_fmaf(rg, accBHN[r], accBXN[r]);
                const float U  = __builtin_amdgcn_exp2f(v2);
                const float Z  = __builtin_amdgcn_exp2f(accBZ[r]);
                const float num = __builtin_fmaf(U, Z + hB_r[r], hB_r[r] - Z);
                const float den = (U + 1.0f) * (Z + 1.0f);
                hB_r[r] = num * __builtin_amdgcn_rcpf(den);
                hOutB[r] = (__bf16)hB_r[r];
            }
            *(bf16x4*)&hA[buf ^ 1][l][w * 16 + 4 * q]  = hOutA;
            *(bf16x4*)&hBt[buf ^ 1][l][w * 16 + 4 * q] = hOutB;

            // ---- queue maintenance (drains free: loads 4+ steps old) ----
            if (s == 3) {
                WAITDEP(qBA); WAITDEP(qBB);
                if (tc + 8 < TSTEPS) {
                    ISSUE_CHUNK(qAA, seqRowA, tc + 8);
                    ISSUE_CHUNK(qAB, seqRowB, tc + 8);
                }
            }
            if (s == 7) {
                WAITDEP(qAA); WAITDEP(qAB);
                if (tc + 12 < TSTEPS) {
                    ISSUE_CHUNK(qBA, seqRowA, tc + 12);
                    ISSUE_CHUNK(qBB, seqRowB, tc + 12);
                }
            }

            // ---- pre-barrier x-proj for t+1, both tiles ----
            {
                const int s1 = s + 1;
                const f32x4* xA = (s1 < 4) ? &qAA[s1 & 3][0]
                                           : (s1 < 8) ? &qBA[s1 & 3][0] : &qAA[0][0];
                const f32x4* xB = (s1 < 4) ? &qAB[s1 & 3][0]
                                           : (s1 < 8) ? &qBB[s1 & 3][0] : &qAB[0][0];
                bf16x8 x1A, x1B;
                #pragma unroll
                for (int j = 0; j < 4; ++j) {
                    x1A[j] = (__bf16)xA[0][j];  x1A[4 + j] = (__bf16)xA[1][j];
                    x1B[j] = (__bf16)xB[0][j];  x1B[4 + j] = (__bf16)xB[1][j];
                }
                accAR  = MFMA16(aI[0], x1A, biasR4);
                accAZ  = MFMA16(aI[1], x1A, biasZ4);
                accAXN = MFMA16(aI[2], x1A, biasXN4);
                accBR  = MFMA16(aI[0], x1B, biasR4);
                accBZ  = MFMA16(aI[1], x1B, biasZ4);
                accBXN = MFMA16(aI[2], x1B, biasXN4);
            }

            WG_BARRIER();   // ONE barrier per pair-step
        }
    }

    if (l < 8) {
        float4 oA = {hA_r[0], hA_r[1], hA_r[2], hA_r[3]};
        float4 oB = {hB_r[0], hB_r[1], hB_r[2], hB_r[3]};
        *(float4*)&out[(size_t)(b0 + l) * HDIM + w * 16 + 4 * q]     = oA;
        *(float4*)&out[(size_t)(b0 + 8 + l) * HDIM + w * 16 + 4 * q] = oB;
    }
}

extern "C" void kernel_launch(void* const* d_in, const int* in_sizes, int n_in,
                              void* d_out, int out_size, void* d_ws, size_t ws_size,
                              hipStream_t stream) {
    const float* seq  = (const float*)d_in[0];
    const float* W_ih = (const float*)d_in[1];
    const float* W_hh = (const float*)d_in[2];
    const float* b_ih = (const float*)d_in[3];
    const float* b_hh = (const float*)d_in[4];
    float* out = (float*)d_out;
    gru_fused_kernel<<<256, 256, 0, stream>>>(seq, W_ih, W_hh, b_ih, b_hh, out);
}

// Round 15
// 484.230 us; speedup vs baseline: 1.3092x; 1.3092x over previous
//
#include <hip/hip_runtime.h>

// GRU: B=4096, T=512, I=32, H=64. One WG per 16-batch tile, 4 waves.
// Wave w owns hidden slice [w*16, w*16+16) for all 3 gates.
// hp^T = W_hh * h^T: A = weight rows in registers, B = h^T from LDS.
//
// R11 = R7 verbatim (best: 237 us/dispatch) — FINAL.
// Session evidence closes all parallelization axes:
//   R6  (8 lockstep waves, redundant MFMA): 405 us (+70%)
//   R8  (x-proj post-barrier reorder):      247 us (+4%)
//   R9  (2 independent WGs/CU):             322 us (+36%)
//   R10 (two-recurrence in-wave ILP):       409 us (+73%)
// Fitting model (matches all rounds): step time is ADDITIVE =
//   issue (~640 cyc: 20 trans x ~16 + ~50 VALU x 2 + 9 MFMA + cvt)
// + non-overlappable latency (~420: ds_read 120, MFMA deps 64,
//   epilogue dep-chain ~150, write+lgkm+barrier ~100) ~= 1110 measured.
// A wave can't overlap its own issue with its own dep stalls; any added
// stream adds its full issue to the same SIMD (R10: VALU 420->895/pair).
// SQ_LDS_BANK_CONFLICT = 6291456 = 256wg x 512step x (8-2)x2readsx4waves
// -> counts inherent b128 8-phase wide access; reads/writes are already
// phase-minimal, padding is a no-op. Irreducible serial core ~1000
// cyc/step -> ~215 us; R7 is within ~10% of it.
//
// Structure: merged-rcp epilogue (one rcp for z-gate+tanh):
//   h' = [U*(Z+h) + (h-Z)] / [(U+1)*(Z+1)],  Z=e^-preZ, U=e^{2(xn+r*hn)}
// r,z weights prescaled by -log2e; n gate by 2log2e (no per-h mul).
// Compiler-proof load pipeline: untracked inline-asm global_load_dwordx4
// bursts (16 loads / 8 steps, 8-step prefetch distance), data-dep
// vmcnt(0) drains, raw lgkmcnt(0)+s_barrier (no vmcnt drain at
// barriers). __launch_bounds__(256,1): occupancy is structurally
// 1 wave/SIMD (256 tiles x 4 waves = 1024 waves = 256 CUs).

#define TSTEPS 512
#define IDIM 32
#define HDIM 64

typedef __bf16 bf16x8 __attribute__((ext_vector_type(8)));
typedef __bf16 bf16x4 __attribute__((ext_vector_type(4)));
typedef float f32x4 __attribute__((ext_vector_type(4)));

#define NLOG2E -1.4426950408889634f
#define TWOLOG2E 2.8853900817779268f

// Two untracked 16B loads (one timestep slice per lane = 8 floats =
// 2x float4) from base+literal offsets.
#define LOADPAIR(dst0, dst1, ptr, off)                                     \
    asm volatile("global_load_dwordx4 %0, %2, off offset:%c3\n\t"          \
                 "global_load_dwordx4 %1, %2, off offset:%c4"              \
        : "=&v"(dst0), "=&v"(dst1)                                         \
        : "v"(ptr), "i"(off), "i"((off) + 16));

// Issue one 8-timestep chunk (1 KiB contiguous per lane) as 16 untracked
// global_load_dwordx4. Stride between timesteps = IDIM*4 = 128 B.
#define ISSUE_CHUNK(qq, baseT) do {                                        \
    const float* _p = seqRow + (size_t)(baseT) * IDIM;                     \
    LOADPAIR(qq[0][0], qq[0][1], _p, 0)                                    \
    LOADPAIR(qq[1][0], qq[1][1], _p, 128)                                  \
    LOADPAIR(qq[2][0], qq[2][1], _p, 256)                                  \
    LOADPAIR(qq[3][0], qq[3][1], _p, 384)                                  \
    LOADPAIR(qq[4][0], qq[4][1], _p, 512)                                  \
    LOADPAIR(qq[5][0], qq[5][1], _p, 640)                                  \
    LOADPAIR(qq[6][0], qq[6][1], _p, 768)                                  \
    LOADPAIR(qq[7][0], qq[7][1], _p, 896)                                  \
} while (0)

// Drain the untracked loads; tie all destinations so no consumer can be
// scheduled above the wait (true data dependence).
#define WAITDEP(qq)                                                        \
    asm volatile("s_waitcnt vmcnt(0)"                                      \
        : "+v"(qq[0][0]), "+v"(qq[0][1]), "+v"(qq[1][0]), "+v"(qq[1][1]), \
          "+v"(qq[2][0]), "+v"(qq[2][1]), "+v"(qq[3][0]), "+v"(qq[3][1]), \
          "+v"(qq[4][0]), "+v"(qq[4][1]), "+v"(qq[5][0]), "+v"(qq[5][1]), \
          "+v"(qq[6][0]), "+v"(qq[6][1]), "+v"(qq[7][0]), "+v"(qq[7][1]))

// Raw barrier: LDS drained manually; NO vmcnt drain (the whole point).
// "memory" clobber pins DS ops (esp. the hOut ds_write) on the correct
// side of the barrier.
#define WG_BARRIER() do {                                                  \
    asm volatile("s_waitcnt lgkmcnt(0)" ::: "memory");                     \
    __builtin_amdgcn_s_barrier();                                          \
} while (0)

__global__ __launch_bounds__(256, 1) void gru_fused_kernel(
    const float* __restrict__ seq, const float* __restrict__ W_ih,
    const float* __restrict__ W_hh, const float* __restrict__ b_ih,
    const float* __restrict__ b_hh, float* __restrict__ out)
{
    __shared__ __bf16 hB[2][16][72];  // h^T double-buffered; 144 B row stride

    const int tid  = threadIdx.x;
    const int w    = tid >> 6;
    const int lane = tid & 63;
    const int l    = lane & 15;       // batch col
    const int q    = lane >> 4;       // quad
    const int b0   = blockIdx.x * 16;

    for (int i = tid; i < 2 * 16 * 72; i += 256)
        (&hB[0][0][0])[i] = (__bf16)0.0f;

    // ---- A-fragments; r,z gates pre-scaled by -log2e; n gate by 2log2e ----
    bf16x8 aH[3][2], aI[3];
    #pragma unroll
    for (int g = 0; g < 3; ++g) {
        const float scl = (g < 2) ? NLOG2E : TWOLOG2E;
        const int row = g * 64 + w * 16 + l;
        #pragma unroll
        for (int kc = 0; kc < 2; ++kc) {
            const float* p = W_hh + row * HDIM + kc * 32 + q * 8;
            #pragma unroll
            for (int j = 0; j < 8; ++j) aH[g][kc][j] = (__bf16)(scl * p[j]);
        }
        const float* pi = W_ih + row * IDIM + q * 8;
        #pragma unroll
        for (int j = 0; j < 8; ++j) aI[g][j] = (__bf16)(scl * pi[j]);
    }

    // ---- bias C-init vectors at this lane's C/D rows (hidden = w*16+4q+r) ----
    f32x4 biasR4, biasZ4, biasXN4, biasHN4;
    #pragma unroll
    for (int r = 0; r < 4; ++r) {
        const int g = w * 16 + 4 * q + r;
        biasR4[r]  = NLOG2E * (b_ih[g]      + b_hh[g]);
        biasZ4[r]  = NLOG2E * (b_ih[64 + g] + b_hh[64 + g]);
        biasXN4[r] = TWOLOG2E * b_ih[128 + g];
        biasHN4[r] = TWOLOG2E * b_hh[128 + g];
    }

    float h[4] = {0.f, 0.f, 0.f, 0.f};

    const float* seqRow = seq + ((size_t)(b0 + l) * TSTEPS) * IDIM + q * 8;

    // ---- 8-step register queues, loaded ONLY via untracked asm loads.
    // qA holds the even chunk (steps tc..tc+7), qB the odd (tc+8..tc+15).
    f32x4 qA[8][2], qB[8][2];
    ISSUE_CHUNK(qA, 0);
    ISSUE_CHUNK(qB, 8);
    WAITDEP(qA);            // vmcnt(0): one-time drain of both chunks
    WAITDEP(qB);            // free (already 0); establishes qB data-dep

    WG_BARRIER();           // hB zero-init visible

    // ---- t=0 x-part (bias-init C) ----
    bf16x8 xb;
    #pragma unroll
    for (int j = 0; j < 4; ++j) {
        xb[j]     = (__bf16)qA[0][0][j];
        xb[4 + j] = (__bf16)qA[0][1][j];
    }
    f32x4 accR  = __builtin_amdgcn_mfma_f32_16x16x32_bf16(aI[0], xb, biasR4, 0, 0, 0);
    f32x4 accZ  = __builtin_amdgcn_mfma_f32_16x16x32_bf16(aI[1], xb, biasZ4, 0, 0, 0);
    f32x4 accXN = __builtin_amdgcn_mfma_f32_16x16x32_bf16(aI[2], xb, biasXN4, 0, 0, 0);

    for (int tc = 0; tc < TSTEPS; tc += 16) {
        #pragma unroll
        for (int s = 0; s < 16; ++s) {
            const int buf = s & 1;  // tc is a multiple of 16

            // post-barrier critical path: h^T fragments
            bf16x8 hb0 = *(const bf16x8*)&hB[buf][l][q * 8];
            bf16x8 hb1 = *(const bf16x8*)&hB[buf][l][32 + q * 8];

            // hb0 group first, then hb1 group: independent chains cover
            // each other's MFMA latency.
            accR = __builtin_amdgcn_mfma_f32_16x16x32_bf16(aH[0][0], hb0, accR, 0, 0, 0);
            accZ = __builtin_amdgcn_mfma_f32_16x16x32_bf16(aH[1][0], hb0, accZ, 0, 0, 0);
            f32x4 accHN = __builtin_amdgcn_mfma_f32_16x16x32_bf16(aH[2][0], hb0, biasHN4, 0, 0, 0);
            accR = __builtin_amdgcn_mfma_f32_16x16x32_bf16(aH[0][1], hb1, accR, 0, 0, 0);
            accZ = __builtin_amdgcn_mfma_f32_16x16x32_bf16(aH[1][1], hb1, accZ, 0, 0, 0);
            accHN = __builtin_amdgcn_mfma_f32_16x16x32_bf16(aH[2][1], hb1, accHN, 0, 0, 0);

            bf16x4 hOut;
            #pragma unroll
            for (int r = 0; r < 4; ++r) {
                // R = e^-preR, Z = e^-preZ (r,z prescaled by -log2e);
                // U = e^{2(xn + rg*hn)} (n-gate prescaled by 2log2e).
                // h' = [U*(Z+h) + (h-Z)] / [(U+1)*(Z+1)]  — one rcp for
                // z-gate + tanh combined. 5 trans/h.
                const float R  = __builtin_amdgcn_exp2f(accR[r]);
                const float rg = __builtin_amdgcn_rcpf(R + 1.0f);
                const float v2 = __builtin_fmaf(rg, accHN[r], accXN[r]);
                const float U  = __builtin_amdgcn_exp2f(v2);
                const float Z  = __builtin_amdgcn_exp2f(accZ[r]);
                const float num = __builtin_fmaf(U, Z + h[r], h[r] - Z);
                const float den = (U + 1.0f) * (Z + 1.0f);
                h[r] = num * __builtin_amdgcn_rcpf(den);
                hOut[r] = (__bf16)h[r];
            }
            *(bf16x4*)&hB[buf ^ 1][l][w * 16 + 4 * q] = hOut;

            // burst pipeline: drain the chunk first needed THIS step (issued
            // 8 steps ago, ~2500+ cyc of cover), then issue the next chunk.
            // All other barriers see zero outstanding vmem.
            if (s == 7) {
                WAITDEP(qB);                              // chunk tc+8 ready
                if (tc + 16 < TSTEPS) ISSUE_CHUNK(qA, tc + 16);
            }
            if (s == 15) {
                WAITDEP(qA);                              // chunk tc+16 ready
                if (tc + 24 < TSTEPS) ISSUE_CHUNK(qB, tc + 24);
            }

            // ---- pre-barrier work for t+1 (h-independent): cvt + x-proj MFMAs ----
            // s+1: slot (s+1)&7 of qA if (s+1)<8 else qB; at s==15 uses qA[0]
            // (refilled with chunk tc+16 at s==7, drained just above). Final
            // step computes a dead x-proj for t=512 from stale regs — harmless.
            {
                const int s1 = s + 1;
                const f32x4* x0 = (s1 < 8) ? &qA[s1 & 7][0]
                                           : (s1 < 16) ? &qB[s1 & 7][0]
                                                       : &qA[0][0];
                bf16x8 xb1;
                #pragma unroll
                for (int j = 0; j < 4; ++j) {
                    xb1[j]     = (__bf16)x0[0][j];
                    xb1[4 + j] = (__bf16)x0[1][j];
                }
                accR  = __builtin_amdgcn_mfma_f32_16x16x32_bf16(aI[0], xb1, biasR4, 0, 0, 0);
                accZ  = __builtin_amdgcn_mfma_f32_16x16x32_bf16(aI[1], xb1, biasZ4, 0, 0, 0);
                accXN = __builtin_amdgcn_mfma_f32_16x16x32_bf16(aI[2], xb1, biasXN4, 0, 0, 0);
            }

            WG_BARRIER();
        }
    }

    float4 o = {h[0], h[1], h[2], h[3]};
    *(float4*)&out[(size_t)(b0 + l) * HDIM + w * 16 + 4 * q] = o;
}

extern "C" void kernel_launch(void* const* d_in, const int* in_sizes, int n_in,
                              void* d_out, int out_size, void* d_ws, size_t ws_size,
                              hipStream_t stream) {
    const float* seq  = (const float*)d_in[0];
    const float* W_ih = (const float*)d_in[1];
    const float* W_hh = (const float*)d_in[2];
    const float* b_ih = (const float*)d_in[3];
    const float* b_hh = (const float*)d_in[4];
    float* out = (float*)d_out;
    gru_fused_kernel<<<256, 256, 0, stream>>>(seq, W_ih, W_hh, b_ih, b_hh, out);
}